// Round 5
// baseline (258.403 us; speedup 1.0000x reference)
//
#include <hip/hip_runtime.h>
#include <math.h>

#define BB 64
#define SS 1024
#define DD 32
#define HH 2
#define DHH 16
#define VV 28
#define QSC 0.3606737602222409f   // 0.25 * log2(e): fold softmax scale + exp2 conversion into Q

typedef __attribute__((ext_vector_type(8))) short bf16x8;
typedef __attribute__((ext_vector_type(4))) float f32x4;

// pack truncated-bf16 of (a,b) into one u32 (a in low half) via v_perm
__device__ __forceinline__ unsigned pack_hi2(float a, float b) {
    return __builtin_amdgcn_perm(__float_as_uint(b), __float_as_uint(a), 0x07060302u);
}

// ---------------- kernel 1: pack Q/K (hi|lo bf16), V^T (hi bf16), e, W2 ----------------
// blocks [0,512): 128 tokens each, 4 waves: wave w -> head w&1, tokens (w>>1)*64+lane
// blocks [512,576): per-row last index; block 576: W2 = wfc@wo
__global__ __launch_bounds__(256) void k_pre(
        const int* __restrict__ x, const float* __restrict__ mask,
        const float* __restrict__ emb, const float* __restrict__ pe,
        const float* __restrict__ wq, const float* __restrict__ bq,
        const float* __restrict__ wk, const float* __restrict__ bk,
        const float* __restrict__ wv, const float* __restrict__ bv,
        const float* __restrict__ wo, const float* __restrict__ bo,
        const float* __restrict__ wfc, const float* __restrict__ bfc,
        int* __restrict__ e, float* __restrict__ W2, float* __restrict__ b2,
        char* __restrict__ qp, char* __restrict__ kp, unsigned short* __restrict__ vp) {
    int bid = blockIdx.x;
    int tid = threadIdx.x;
    if (bid < 512) {
        __shared__ unsigned short sVt[32 * 128];
        int wave = tid >> 6, lane = tid & 63;
        int hh = __builtin_amdgcn_readfirstlane(wave & 1);   // wave-uniform -> weight s_loads
        int t = (wave >> 1) * 64 + lane;
        int idx = bid * 128 + t;
        int b = idx >> 10, s = idx & 1023;
        float nm = (mask[b * SS + (s >= 3 ? s - 3 : 0)] != 0.0f) ? 1.0f : 0.0f;
        int tok = x[idx];
        float h[DD];
#pragma unroll
        for (int i = 0; i < DD; i++) h[i] = (emb[tok * DD + i] + pe[s * DD + i]) * nm;
        int rbase = hh * 16;
        float acc[16];

        // ---- Q: scaled, hi|lo packed 64B row ----
#pragma unroll
        for (int ii = 0; ii < 16; ii++) {
            float a = bq[rbase + ii];
#pragma unroll
            for (int j = 0; j < DD; j++) a += h[j] * wq[(rbase + ii) * DD + j];
            acc[ii] = a * QSC;
        }
        {
            char* dst = qp + ((size_t)((b * 2 + hh) * 1024 + s)) * 64;
            unsigned w0[8], w1[8];
#pragma unroll
            for (int wd = 0; wd < 8; wd++) {
                float a0 = acc[2 * wd], a1 = acc[2 * wd + 1];
                w0[wd] = pack_hi2(a0, a1);
                float l0 = a0 - __uint_as_float(__float_as_uint(a0) & 0xFFFF0000u);
                float l1 = a1 - __uint_as_float(__float_as_uint(a1) & 0xFFFF0000u);
                w1[wd] = pack_hi2(l0, l1);
            }
            ((uint4*)dst)[0] = uint4{w0[0], w0[1], w0[2], w0[3]};
            ((uint4*)dst)[1] = uint4{w0[4], w0[5], w0[6], w0[7]};
            ((uint4*)dst)[2] = uint4{w1[0], w1[1], w1[2], w1[3]};
            ((uint4*)dst)[3] = uint4{w1[4], w1[5], w1[6], w1[7]};
        }
        // ---- K: unscaled, hi|lo packed ----
#pragma unroll
        for (int ii = 0; ii < 16; ii++) {
            float a = bk[rbase + ii];
#pragma unroll
            for (int j = 0; j < DD; j++) a += h[j] * wk[(rbase + ii) * DD + j];
            acc[ii] = a;
        }
        {
            char* dst = kp + ((size_t)((b * 2 + hh) * 1024 + s)) * 64;
            unsigned w0[8], w1[8];
#pragma unroll
            for (int wd = 0; wd < 8; wd++) {
                float a0 = acc[2 * wd], a1 = acc[2 * wd + 1];
                w0[wd] = pack_hi2(a0, a1);
                float l0 = a0 - __uint_as_float(__float_as_uint(a0) & 0xFFFF0000u);
                float l1 = a1 - __uint_as_float(__float_as_uint(a1) & 0xFFFF0000u);
                w1[wd] = pack_hi2(l0, l1);
            }
            ((uint4*)dst)[0] = uint4{w0[0], w0[1], w0[2], w0[3]};
            ((uint4*)dst)[1] = uint4{w0[4], w0[5], w0[6], w0[7]};
            ((uint4*)dst)[2] = uint4{w1[0], w1[1], w1[2], w1[3]};
            ((uint4*)dst)[3] = uint4{w1[4], w1[5], w1[6], w1[7]};
        }
        // ---- V: hi-only bf16, transposed [row=h*16+dh][key] via LDS ----
#pragma unroll
        for (int ii = 0; ii < 16; ii++) {
            float a = bv[rbase + ii];
#pragma unroll
            for (int j = 0; j < DD; j++) a += h[j] * wv[(rbase + ii) * DD + j];
            sVt[(rbase + ii) * 128 + t] = (unsigned short)(__float_as_uint(a) >> 16);
        }
        __syncthreads();
        {
            int row = tid >> 3, part = tid & 7;
            int bb = bid >> 3, s0v = (bid & 7) * 128;
            const unsigned short* src = sVt + row * 128 + part * 16;
            uint4 d0 = ((const uint4*)src)[0];
            uint4 d1 = ((const uint4*)(src + 8))[0];
            unsigned short* dst = vp + ((size_t)(bb * 32 + row)) * 1024 + s0v + part * 16;
            ((uint4*)dst)[0] = d0;
            ((uint4*)dst)[1] = d1;
        }
    } else if (bid < 576) {
        int b = bid - 512;
        int lm = -1;
        for (int s = tid; s < SS; s += 256)
            if (mask[b * SS + s] != 0.0f) lm = s;
        __shared__ int red[256];
        red[tid] = lm;
        __syncthreads();
        for (int off = 128; off > 0; off >>= 1) {
            if (tid < off) red[tid] = max(red[tid], red[tid + off]);
            __syncthreads();
        }
        if (tid == 0) {
            int last = red[0];
            int ee = last;
            if (last < SS - 1) ee = min(last + 3, SS - 1);
            e[b] = ee;   // kmax = e+1
        }
    } else {
        for (int t2 = tid; t2 < VV * DD + VV; t2 += 256) {
            if (t2 < VV * DD) {
                int vv = t2 / DD, i = t2 % DD;
                float a = 0.0f;
                for (int j = 0; j < DD; j++) a += wfc[vv * DD + j] * wo[j * DD + i];
                W2[t2] = a;
            } else {
                int vv = t2 - VV * DD;
                float a = bfc[vv];
                for (int j = 0; j < DD; j++) a += wfc[vv * DD + j] * bo[j];
                b2[vv] = a;
            }
        }
    }
}

// ---------------- kernel 2: barrier-free MFMA flash attention + fused FC ----------------
// grid 2048: b = id&63, qt = id>>6. Block: 32 queries x 2 heads, 4 waves.
// K-loop: 64 keys/iter, key<->lane map: tile t, lane col c -> key kt+4c+t.
__global__ __launch_bounds__(256) void k_attn(
        const char* __restrict__ qp, const char* __restrict__ kp,
        const unsigned short* __restrict__ vp, const int* __restrict__ e,
        const float* __restrict__ W2, const float* __restrict__ b2,
        float* __restrict__ out) {
    // smem: [0,9216) P (4 waves x 16 rows x 144B), aliased by Ob (32x36 f32) after loop
    //       [9216,13248) sW 28x36 f32 ; [13248,13360) sb
    __shared__ __align__(16) char smem[13376];
    float* Ob = (float*)smem;
    float* sW = (float*)(smem + 9216);
    float* sb = (float*)(smem + 13248);

    int tid = threadIdx.x;
    int b = blockIdx.x & 63, qt = blockIdx.x >> 6;
    int s0 = qt * 32;
    int wave = tid >> 6, lane = tid & 63, quad = lane >> 4, c = lane & 15;
    int h = wave & 1;
    int qbase = s0 + (wave >> 1) * 16;
    int kmax = e[b] + 1;

    for (int i = tid; i < VV * DD; i += 256) sW[(i >> 5) * 36 + (i & 31)] = W2[i];
    if (tid < VV) sb[tid] = b2[tid];

    char* Pw = smem + wave * 2304;
    char* Pwrt = Pw + (quad * 4) * 144 + c * 8;   // P write base (+r*144)
    const char* Pra = Pw + c * 144 + quad * 16;   // P A-frag read base

    bf16x8 aQ = *(const bf16x8*)(qp + ((size_t)((b * 2 + h) * 1024 + qbase + c)) * 64 + quad * 16);

    const char* kb = kp + ((size_t)((b * 2 + h) * 1024 + 4 * c)) * 64 + (quad & 1) * 16;
    const unsigned short* vb = vp + ((size_t)(b * 32 + h * 16 + c)) * 1024 + quad * 8;

    f32x4 accO = {0.0f, 0.0f, 0.0f, 0.0f};
    const f32x4 z4 = {0.0f, 0.0f, 0.0f, 0.0f};
    float l_[4] = {0.0f, 0.0f, 0.0f, 0.0f};
    float m = -3e38f;

    for (int kt = 0; kt < kmax; kt += 64) {
        const char* ktb = kb + (size_t)kt * 64;
        f32x4 st[4];
#pragma unroll
        for (int t = 0; t < 4; t++) {
            bf16x8 bkh = *(const bf16x8*)(ktb + t * 64);
            bf16x8 bkl = *(const bf16x8*)(ktb + t * 64 + 32);
            f32x4 sv = __builtin_amdgcn_mfma_f32_16x16x32_bf16(aQ, bkl, z4, 0, 0, 0);
            sv = __builtin_amdgcn_mfma_f32_16x16x32_bf16(aQ, bkh, sv, 0, 0, 0);
            int key = kt + 4 * c + t;
            if (key >= kmax) { sv[0] = -3e38f; sv[1] = -3e38f; sv[2] = -3e38f; sv[3] = -3e38f; }
            st[t] = sv;
        }
        // tile-shared max (16q x 64k): safe for softmax, cheap reduce
        float tm0 = fmaxf(fmaxf(st[0][0], st[0][1]), fmaxf(st[0][2], st[0][3]));
        float tm1 = fmaxf(fmaxf(st[1][0], st[1][1]), fmaxf(st[1][2], st[1][3]));
        float tm2 = fmaxf(fmaxf(st[2][0], st[2][1]), fmaxf(st[2][2], st[2][3]));
        float tm3 = fmaxf(fmaxf(st[3][0], st[3][1]), fmaxf(st[3][2], st[3][3]));
        float tmax = fmaxf(fmaxf(tm0, tm1), fmaxf(tm2, tm3));
#pragma unroll
        for (int d = 1; d < 64; d <<= 1) tmax = fmaxf(tmax, __shfl_xor(tmax, d));
        float mn = fmaxf(m, tmax);
        float sc = exp2f(m - mn);
        m = mn;
        float p[4][4];
#pragma unroll
        for (int t = 0; t < 4; t++)
#pragma unroll
            for (int r = 0; r < 4; r++) p[t][r] = exp2f(st[t][r] - mn);
#pragma unroll
        for (int r = 0; r < 4; r++) {
            l_[r] = l_[r] * sc + ((p[0][r] + p[1][r]) + (p[2][r] + p[3][r]));
            accO[r] *= sc;
        }
        // P transpose: lane holds keys 4c..4c+3 for rows quad*4+r -> one b64 per row
#pragma unroll
        for (int r = 0; r < 4; r++) {
            unsigned lo = pack_hi2(p[0][r], p[1][r]);
            unsigned hi = pack_hi2(p[2][r], p[3][r]);
            *(uint2*)(Pwrt + r * 144) = uint2{lo, hi};
        }
        bf16x8 aP0 = *(const bf16x8*)(Pra);
        bf16x8 aP1 = *(const bf16x8*)(Pra + 64);
        const unsigned short* vkt = vb + kt;
        bf16x8 bv0 = *(const bf16x8*)(vkt);
        bf16x8 bv1 = *(const bf16x8*)(vkt + 32);
        accO = __builtin_amdgcn_mfma_f32_16x16x32_bf16(aP0, bv0, accO, 0, 0, 0);
        accO = __builtin_amdgcn_mfma_f32_16x16x32_bf16(aP1, bv1, accO, 0, 0, 0);
    }

    // l: reduce over the 16 key-columns
#pragma unroll
    for (int d = 1; d < 16; d <<= 1) {
#pragma unroll
        for (int r = 0; r < 4; r++) l_[r] += __shfl_xor(l_[r], d, 16);
    }
    __syncthreads();   // all waves done with P before aliasing as Ob
#pragma unroll
    for (int r = 0; r < 4; r++)
        Ob[((wave >> 1) * 16 + quad * 4 + r) * 36 + h * DHH + c] = accO[r] / l_[r];
    __syncthreads();

    // ---- fused FC: out = O @ W2^T + b2 ----
    int qloc = tid >> 3, j = tid & 7;
    const float* orow = Ob + qloc * 36;
    float ov[DD];
#pragma unroll
    for (int i = 0; i < DD; i += 4) {
        float4 t4 = *(const float4*)(orow + i);
        ov[i] = t4.x; ov[i + 1] = t4.y; ov[i + 2] = t4.z; ov[i + 3] = t4.w;
    }
    size_t obase = (size_t)(b * SS + s0 + qloc) * VV;
#pragma unroll
    for (int jj = 0; jj < 4; jj++) {
        int vv = j + jj * 8;
        if (vv < VV) {
            float a = sb[vv];
#pragma unroll
            for (int d2 = 0; d2 < DD; d2 += 4) {
                float4 w4 = *(const float4*)(sW + vv * 36 + d2);
                a += ov[d2] * w4.x + ov[d2 + 1] * w4.y + ov[d2 + 2] * w4.z + ov[d2 + 3] * w4.w;
            }
            out[obase + vv] = a;
        }
    }
}

extern "C" void kernel_launch(void* const* d_in, const int* in_sizes, int n_in,
                              void* d_out, int out_size, void* d_ws, size_t ws_size,
                              hipStream_t stream) {
    const int*   x    = (const int*)d_in[0];
    const float* mask = (const float*)d_in[1];
    const float* emb  = (const float*)d_in[2];
    const float* pe   = (const float*)d_in[3];
    const float* wq   = (const float*)d_in[4];
    const float* bq   = (const float*)d_in[5];
    const float* wk   = (const float*)d_in[6];
    const float* bk   = (const float*)d_in[7];
    const float* wv   = (const float*)d_in[8];
    const float* bv   = (const float*)d_in[9];
    const float* wo   = (const float*)d_in[10];
    const float* bo   = (const float*)d_in[11];
    const float* wfc  = (const float*)d_in[12];
    const float* bfc  = (const float*)d_in[13];
    float* out = (float*)d_out;

    char* ws = (char*)d_ws;
    int*   e  = (int*)ws;                                   // 256 B
    float* W2 = (float*)(ws + 256);                         // 3584 B
    float* b2 = (float*)(ws + 3840);                        // 112 B
    char*  qp = ws + 4096;                                  // 8 MiB: [b][h][s][qh16|ql16]
    char*  kp = qp + (size_t)BB * HH * SS * 64;             // 8 MiB: [b][h][key][kh16|kl16]
    unsigned short* vp = (unsigned short*)(kp + (size_t)BB * HH * SS * 64);  // 4 MiB: [b][h*16+dh][key]

    hipLaunchKernelGGL(k_pre, dim3(577), dim3(256), 0, stream,
                       x, mask, emb, pe, wq, bq, wk, bk, wv, bv, wo, bo, wfc, bfc,
                       e, W2, b2, qp, kp, vp);
    hipLaunchKernelGGL(k_attn, dim3(BB * (SS / 32)), dim3(256), 0, stream,
                       qp, kp, vp, e, W2, b2, out);
}

// Round 6
// 215.641 us; speedup vs baseline: 1.1983x; 1.1983x over previous
//
#include <hip/hip_runtime.h>
#include <math.h>

#define BB 64
#define SS 1024
#define DD 32
#define HH 2
#define DHH 16
#define VV 28
#define QSC 0.3606737602222409f   // 0.25 * log2(e)
#define KCH 256
#define NSPLIT 4

typedef __attribute__((ext_vector_type(8))) short bf16x8;
typedef __attribute__((ext_vector_type(4))) float f32x4;

__device__ __forceinline__ unsigned pack_hi2(float a, float b) {
    return __builtin_amdgcn_perm(__float_as_uint(b), __float_as_uint(a), 0x07060302u);
}
__device__ __forceinline__ float trunc_hi(float a) {
    return __uint_as_float(__float_as_uint(a) & 0xFFFF0000u);
}
__device__ __forceinline__ bf16x8 as_bf16x8(uint4 u) {
    union { uint4 u; bf16x8 v; } cv; cv.u = u; return cv.v;
}

// ---------------- kernel 1: MFMA QKV projection + pack; e; W2 ----------------
// blocks [0,512): 128 tokens each. [512,576): last-index. 576: W2.
__global__ __launch_bounds__(256) void k_pre(
        const int* __restrict__ x, const float* __restrict__ mask,
        const float* __restrict__ emb, const float* __restrict__ pe,
        const float* __restrict__ wq, const float* __restrict__ bq,
        const float* __restrict__ wk, const float* __restrict__ bk,
        const float* __restrict__ wv, const float* __restrict__ bv,
        const float* __restrict__ wo, const float* __restrict__ bo,
        const float* __restrict__ wfc, const float* __restrict__ bfc,
        int* __restrict__ e, float* __restrict__ W2, float* __restrict__ b2,
        char* __restrict__ qp, char* __restrict__ kp, unsigned short* __restrict__ vp) {
    int bid = blockIdx.x;
    int tid = threadIdx.x;
    if (bid < 512) {
        // hHi/hLo: 128 tokens x 80B (32 bf16 dims + pad); Cb: per-wave 32x17 f32
        __shared__ __align__(16) char hbuf[20480];
        __shared__ __align__(16) float Cb[4][32 * 17 + 4];
        char* hHi = hbuf;
        char* hLo = hbuf + 10240;
        int wave = tid >> 6, lane = tid & 63;
        int c = lane & 15, kq = lane >> 4;

        // ---- phase A: h = (emb[x]+pe)*nm -> LDS hi/lo bf16 ----
        {
            int tt = tid >> 1, dhalf = (tid & 1) * 16;
            int idx = bid * 128 + tt;
            int b = idx >> 10, s = idx & 1023;
            float nm = (mask[b * SS + (s >= 3 ? s - 3 : 0)] != 0.0f) ? 1.0f : 0.0f;
            int tok = x[idx];
            float h[16];
#pragma unroll
            for (int i = 0; i < 16; i++)
                h[i] = (emb[tok * DD + dhalf + i] + pe[s * DD + dhalf + i]) * nm;
            unsigned wh[8], wl[8];
#pragma unroll
            for (int wd = 0; wd < 8; wd++) {
                float a0 = h[2 * wd], a1 = h[2 * wd + 1];
                wh[wd] = pack_hi2(a0, a1);
                wl[wd] = pack_hi2(a0 - trunc_hi(a0), a1 - trunc_hi(a1));
            }
            char* dh_ = hHi + tt * 80 + dhalf * 2;
            ((uint4*)dh_)[0] = uint4{wh[0], wh[1], wh[2], wh[3]};
            ((uint4*)dh_)[1] = uint4{wh[4], wh[5], wh[6], wh[7]};
            char* dl_ = hLo + tt * 80 + dhalf * 2;
            ((uint4*)dl_)[0] = uint4{wl[0], wl[1], wl[2], wl[3]};
            ((uint4*)dl_)[1] = uint4{wl[4], wl[5], wl[6], wl[7]};
        }
        __syncthreads();

        // ---- A-frags: wave's 2 token-tiles (tokens wave*32 .. +31) ----
        int mt0 = wave * 2;
        bf16x8 aHh[2], aHl[2];
#pragma unroll
        for (int t2 = 0; t2 < 2; t2++) {
            int off = ((mt0 + t2) * 16 + c) * 80 + kq * 16;
            aHh[t2] = *(const bf16x8*)(hHi + off);
            aHl[t2] = *(const bf16x8*)(hLo + off);
        }
        int blk_b = (bid * 128) >> 10;
        int s_base = (bid * 128) & 1023;
        const f32x4 z4 = {0.0f, 0.0f, 0.0f, 0.0f};

#pragma unroll
        for (int M = 0; M < 3; M++) {
            const float* W    = M == 0 ? wq : (M == 1 ? wk : wv);
            const float* bias = M == 0 ? bq : (M == 1 ? bk : bv);
            // ---- B-frags (hi/lo) for both out-tiles ----
            bf16x8 Bh[2], Bl[2];
            float bv_[2];
#pragma unroll
            for (int nt = 0; nt < 2; nt++) {
                const float* wrow = W + (nt * 16 + c) * DD + kq * 8;
                float4 wa = ((const float4*)wrow)[0];
                float4 wb = ((const float4*)wrow)[1];
                float f[8] = {wa.x, wa.y, wa.z, wa.w, wb.x, wb.y, wb.z, wb.w};
                unsigned uh[4], ul[4];
#pragma unroll
                for (int wd = 0; wd < 4; wd++) {
                    float a0 = f[2 * wd], a1 = f[2 * wd + 1];
                    uh[wd] = pack_hi2(a0, a1);
                    ul[wd] = pack_hi2(a0 - trunc_hi(a0), a1 - trunc_hi(a1));
                }
                Bh[nt] = as_bf16x8(uint4{uh[0], uh[1], uh[2], uh[3]});
                Bl[nt] = as_bf16x8(uint4{ul[0], ul[1], ul[2], ul[3]});
                bv_[nt] = bias[nt * 16 + c];
            }
#pragma unroll
            for (int nt = 0; nt < 2; nt++) {
#pragma unroll
                for (int t2 = 0; t2 < 2; t2++) {
                    f32x4 acc = __builtin_amdgcn_mfma_f32_16x16x32_bf16(aHh[t2], Bh[nt], z4, 0, 0, 0);
                    acc = __builtin_amdgcn_mfma_f32_16x16x32_bf16(aHl[t2], Bh[nt], acc, 0, 0, 0);
                    acc = __builtin_amdgcn_mfma_f32_16x16x32_bf16(aHh[t2], Bl[nt], acc, 0, 0, 0);
#pragma unroll
                    for (int r = 0; r < 4; r++) {
                        float val = acc[r] + bv_[nt];
                        if (M == 0) val *= QSC;
                        Cb[wave][(t2 * 16 + kq * 4 + r) * 17 + c] = val;
                    }
                }
                // ---- pack this head's 32 tokens (wave-local, no barrier needed) ----
                if (M < 2) {
                    int tl = lane >> 1, half = lane & 1;
                    float f[8];
#pragma unroll
                    for (int j = 0; j < 8; j++) f[j] = Cb[wave][tl * 17 + half * 8 + j];
                    unsigned hh[4], ll[4];
#pragma unroll
                    for (int wd = 0; wd < 4; wd++) {
                        float a0 = f[2 * wd], a1 = f[2 * wd + 1];
                        hh[wd] = pack_hi2(a0, a1);
                        ll[wd] = pack_hi2(a0 - trunc_hi(a0), a1 - trunc_hi(a1));
                    }
                    int s = s_base + wave * 32 + tl;
                    char* dst = (M == 0 ? qp : kp)
                              + ((size_t)((blk_b * 2 + nt) * 1024 + s)) * 64;
                    *(uint4*)(dst + half * 16)      = uint4{hh[0], hh[1], hh[2], hh[3]};
                    *(uint4*)(dst + 32 + half * 16) = uint4{ll[0], ll[1], ll[2], ll[3]};
                } else {
                    int dh = lane >> 2, kg = lane & 3;
                    unsigned hh[4];
#pragma unroll
                    for (int wd = 0; wd < 4; wd++) {
                        float f0 = Cb[wave][(kg * 8 + 2 * wd) * 17 + dh];
                        float f1 = Cb[wave][(kg * 8 + 2 * wd + 1) * 17 + dh];
                        hh[wd] = pack_hi2(f0, f1);
                    }
                    int srow = blk_b * 32 + nt * 16 + dh;
                    int scol = s_base + wave * 32 + kg * 8;
                    *(uint4*)(vp + (size_t)srow * 1024 + scol) = uint4{hh[0], hh[1], hh[2], hh[3]};
                }
            }
        }
    } else if (bid < 576) {
        int b = bid - 512;
        int lm = -1;
        for (int s = tid; s < SS; s += 256)
            if (mask[b * SS + s] != 0.0f) lm = s;
        __shared__ int red[256];
        red[tid] = lm;
        __syncthreads();
        for (int off = 128; off > 0; off >>= 1) {
            if (tid < off) red[tid] = max(red[tid], red[tid + off]);
            __syncthreads();
        }
        if (tid == 0) {
            int last = red[0];
            int ee = last;
            if (last < SS - 1) ee = min(last + 3, SS - 1);
            e[b] = ee;   // kmax = e+1
        }
    } else {
        for (int t2 = tid; t2 < VV * DD + VV; t2 += 256) {
            if (t2 < VV * DD) {
                int vv = t2 / DD, i = t2 % DD;
                float a = 0.0f;
                for (int j = 0; j < DD; j++) a += wfc[vv * DD + j] * wo[j * DD + i];
                W2[t2] = a;
            } else {
                int vv = t2 - VV * DD;
                float a = bfc[vv];
                for (int j = 0; j < DD; j++) a += wfc[vv * DD + j] * bo[j];
                b2[vv] = a;
            }
        }
    }
}

// ---------------- kernel 2: split-K MFMA flash attention (partials) ----------------
// grid (32 qt, 64 b, 4 sp). Split sp covers keys [sp*256, sp*256+256) ∩ [0,kmax).
__global__ __launch_bounds__(256) void k_attn(
        const char* __restrict__ qp, const char* __restrict__ kp,
        const unsigned short* __restrict__ vp, const int* __restrict__ e,
        float* __restrict__ pm, float* __restrict__ pl, float* __restrict__ pacc) {
    __shared__ __align__(16) char Pb[9216];
    int tid = threadIdx.x;
    int qt = blockIdx.x, b = blockIdx.y, sp = blockIdx.z;
    int kmax = e[b] + 1;
    int k0 = sp * KCH;
    if (k0 >= kmax) return;                       // block-uniform early exit
    int k1 = min(k0 + KCH, kmax);

    int wave = tid >> 6, lane = tid & 63, quad = lane >> 4, c = lane & 15;
    int h = wave & 1;
    int qbase = qt * 32 + (wave >> 1) * 16;
    int bh = b * 2 + h;

    char* Pw = Pb + wave * 2304;
    char* Pwrt = Pw + (quad * 4) * 144 + c * 8;
    const char* Pra = Pw + c * 144 + quad * 16;

    bf16x8 aQ = *(const bf16x8*)(qp + ((size_t)(bh * 1024 + qbase + c)) * 64 + quad * 16);
    const char* kb = kp + ((size_t)(bh * 1024 + 4 * c)) * 64 + (quad & 1) * 16;
    const unsigned short* vb = vp + ((size_t)(b * 32 + h * 16 + c)) * 1024 + quad * 8;

    f32x4 accO = {0.0f, 0.0f, 0.0f, 0.0f};
    const f32x4 z4 = {0.0f, 0.0f, 0.0f, 0.0f};
    float l_[4] = {0.0f, 0.0f, 0.0f, 0.0f};
    float m = -3e38f;

    for (int kt = k0; kt < k1; kt += 64) {
        const char* ktb = kb + (size_t)kt * 64;
        f32x4 st[4];
#pragma unroll
        for (int t = 0; t < 4; t++) {
            bf16x8 bkh = *(const bf16x8*)(ktb + t * 64);
            bf16x8 bkl = *(const bf16x8*)(ktb + t * 64 + 32);
            f32x4 sv = __builtin_amdgcn_mfma_f32_16x16x32_bf16(aQ, bkl, z4, 0, 0, 0);
            sv = __builtin_amdgcn_mfma_f32_16x16x32_bf16(aQ, bkh, sv, 0, 0, 0);
            int key = kt + 4 * c + t;
            if (key >= kmax) { sv[0] = -3e38f; sv[1] = -3e38f; sv[2] = -3e38f; sv[3] = -3e38f; }
            st[t] = sv;
        }
        float tm0 = fmaxf(fmaxf(st[0][0], st[0][1]), fmaxf(st[0][2], st[0][3]));
        float tm1 = fmaxf(fmaxf(st[1][0], st[1][1]), fmaxf(st[1][2], st[1][3]));
        float tm2 = fmaxf(fmaxf(st[2][0], st[2][1]), fmaxf(st[2][2], st[2][3]));
        float tm3 = fmaxf(fmaxf(st[3][0], st[3][1]), fmaxf(st[3][2], st[3][3]));
        float tmax = fmaxf(fmaxf(tm0, tm1), fmaxf(tm2, tm3));
#pragma unroll
        for (int d = 1; d < 64; d <<= 1) tmax = fmaxf(tmax, __shfl_xor(tmax, d));
        float mn = fmaxf(m, tmax);
        float sc = exp2f(m - mn);
        m = mn;
        float p[4][4];
#pragma unroll
        for (int t = 0; t < 4; t++)
#pragma unroll
            for (int r = 0; r < 4; r++) p[t][r] = exp2f(st[t][r] - mn);
#pragma unroll
        for (int r = 0; r < 4; r++) {
            l_[r] = l_[r] * sc + ((p[0][r] + p[1][r]) + (p[2][r] + p[3][r]));
            accO[r] *= sc;
        }
#pragma unroll
        for (int r = 0; r < 4; r++) {
            unsigned lo = pack_hi2(p[0][r], p[1][r]);
            unsigned hi = pack_hi2(p[2][r], p[3][r]);
            *(uint2*)(Pwrt + r * 144) = uint2{lo, hi};
        }
        bf16x8 aP0 = *(const bf16x8*)(Pra);
        bf16x8 aP1 = *(const bf16x8*)(Pra + 64);
        const unsigned short* vkt = vb + kt;
        bf16x8 bv0 = *(const bf16x8*)(vkt);
        bf16x8 bv1 = *(const bf16x8*)(vkt + 32);
        accO = __builtin_amdgcn_mfma_f32_16x16x32_bf16(aP0, bv0, accO, 0, 0, 0);
        accO = __builtin_amdgcn_mfma_f32_16x16x32_bf16(aP1, bv1, accO, 0, 0, 0);
    }

#pragma unroll
    for (int d = 1; d < 16; d <<= 1) {
#pragma unroll
        for (int r = 0; r < 4; r++) l_[r] += __shfl_xor(l_[r], d, 16);
    }
#pragma unroll
    for (int r = 0; r < 4; r++) {
        int q = qbase + quad * 4 + r;
        size_t pi = ((size_t)bh * SS + q) * NSPLIT + sp;
        pacc[pi * 16 + c] = accO[r];
        if (c == 0) { pm[pi] = m; pl[pi] = l_[r]; }
    }
}

// ---------------- kernel 3: combine partials + out = O @ W2^T + b2 ----------------
__global__ __launch_bounds__(256) void k_fc(
        const float* __restrict__ pm, const float* __restrict__ pl,
        const float* __restrict__ pacc, const int* __restrict__ e,
        const float* __restrict__ W2, const float* __restrict__ b2,
        float* __restrict__ out) {
    __shared__ float sW[VV * 36];
    __shared__ float sb[VV];
    for (int i = threadIdx.x; i < VV * DD; i += 256) sW[(i >> 5) * 36 + (i & 31)] = W2[i];
    if (threadIdx.x < VV) sb[threadIdx.x] = b2[threadIdx.x];
    __syncthreads();

    int idx = blockIdx.x * 256 + threadIdx.x;    // [0, B*S)
    int b = idx >> 10, s = idx & 1023;
    int nsp = min(NSPLIT, (e[b] + 1 + KCH - 1) / KCH);

    float o_[DD];
#pragma unroll
    for (int h = 0; h < HH; h++) {
        size_t base = ((size_t)(b * 2 + h) * SS + s) * NSPLIT;
        float mm[NSPLIT], ll[NSPLIT];
#pragma unroll
        for (int sp = 0; sp < NSPLIT; sp++) {
            if (sp < nsp) { mm[sp] = pm[base + sp]; ll[sp] = pl[base + sp]; }
            else          { mm[sp] = -3e38f;        ll[sp] = 0.0f; }
        }
        float M = fmaxf(fmaxf(mm[0], mm[1]), fmaxf(mm[2], mm[3]));
        float w[NSPLIT];
        float l = 0.0f;
#pragma unroll
        for (int sp = 0; sp < NSPLIT; sp++) {
            w[sp] = (sp < nsp) ? exp2f(mm[sp] - M) : 0.0f;
            l += ll[sp] * w[sp];
        }
        float inv = 1.0f / l;
#pragma unroll
        for (int i = 0; i < DHH; i++) {
            float a = 0.0f;
#pragma unroll
            for (int sp = 0; sp < NSPLIT; sp++) {
                if (sp < nsp) a += pacc[(base + sp) * 16 + i] * w[sp];
            }
            o_[h * DHH + i] = a * inv;
        }
    }
#pragma unroll
    for (int vv = 0; vv < VV; vv++) {
        float a = sb[vv];
#pragma unroll
        for (int d = 0; d < DD; d++) a += o_[d] * sW[vv * 36 + d];
        out[(size_t)idx * VV + vv] = a;
    }
}

extern "C" void kernel_launch(void* const* d_in, const int* in_sizes, int n_in,
                              void* d_out, int out_size, void* d_ws, size_t ws_size,
                              hipStream_t stream) {
    const int*   x    = (const int*)d_in[0];
    const float* mask = (const float*)d_in[1];
    const float* emb  = (const float*)d_in[2];
    const float* pe   = (const float*)d_in[3];
    const float* wq   = (const float*)d_in[4];
    const float* bq   = (const float*)d_in[5];
    const float* wk   = (const float*)d_in[6];
    const float* bk   = (const float*)d_in[7];
    const float* wv   = (const float*)d_in[8];
    const float* bv   = (const float*)d_in[9];
    const float* wo   = (const float*)d_in[10];
    const float* bo   = (const float*)d_in[11];
    const float* wfc  = (const float*)d_in[12];
    const float* bfc  = (const float*)d_in[13];
    float* out = (float*)d_out;

    char* ws = (char*)d_ws;
    int*   e  = (int*)ws;                                     // 256 B
    float* W2 = (float*)(ws + 256);
    float* b2 = (float*)(ws + 3840);
    char*  qp = ws + 4096;                                    // 8 MiB
    char*  kp = qp + (size_t)BB * HH * SS * 64;               // 8 MiB
    unsigned short* vp = (unsigned short*)(kp + (size_t)BB * HH * SS * 64);  // 4 MiB
    float* pm   = (float*)(ws + 4096 + 20971520);             // 2 MiB
    float* pl   = pm + (size_t)BB * HH * SS * NSPLIT;         // 2 MiB
    float* pacc = pl + (size_t)BB * HH * SS * NSPLIT;         // 32 MiB

    hipLaunchKernelGGL(k_pre, dim3(577), dim3(256), 0, stream,
                       x, mask, emb, pe, wq, bq, wk, bk, wv, bv, wo, bo, wfc, bfc,
                       e, W2, b2, qp, kp, vp);
    hipLaunchKernelGGL(k_attn, dim3(SS / 32, BB, NSPLIT), dim3(256), 0, stream,
                       qp, kp, vp, e, pm, pl, pacc);
    hipLaunchKernelGGL(k_fc, dim3(BB * SS / 256), dim3(256), 0, stream,
                       pm, pl, pacc, e, W2, b2, out);
}

// Round 7
// 205.525 us; speedup vs baseline: 1.2573x; 1.0492x over previous
//
#include <hip/hip_runtime.h>
#include <math.h>

#define BB 64
#define SS 1024
#define DD 32
#define HH 2
#define DHH 16
#define VV 28
#define QSC 0.3606737602222409f   // 0.25 * log2(e)
#define KCH 256
#define NSPLIT 4

typedef __attribute__((ext_vector_type(8))) short bf16x8;
typedef __attribute__((ext_vector_type(4))) float f32x4;

__device__ __forceinline__ unsigned pack_hi2(float a, float b) {
    return __builtin_amdgcn_perm(__float_as_uint(b), __float_as_uint(a), 0x07060302u);
}
__device__ __forceinline__ float trunc_hi(float a) {
    return __uint_as_float(__float_as_uint(a) & 0xFFFF0000u);
}
__device__ __forceinline__ unsigned short bf_rtne(float x) {
    unsigned u = __float_as_uint(x);
    return (unsigned short)((u + 0x7FFFu + ((u >> 16) & 1u)) >> 16);
}
__device__ __forceinline__ float bf2f(unsigned short u) {
    return __uint_as_float(((unsigned)u) << 16);
}
__device__ __forceinline__ bf16x8 as_bf16x8(uint4 u) {
    union { uint4 u; bf16x8 v; } cv; cv.u = u; return cv.v;
}

// ---------------- kernel 1: MFMA QKV projection + pack; e; W2 ----------------
// blocks [0,1024): 64 tokens each. [1024,1088): last-index. 1088: W2.
__global__ __launch_bounds__(256) void k_pre(
        const int* __restrict__ x, const float* __restrict__ mask,
        const float* __restrict__ emb, const float* __restrict__ pe,
        const float* __restrict__ wq, const float* __restrict__ bq,
        const float* __restrict__ wk, const float* __restrict__ bk,
        const float* __restrict__ wv, const float* __restrict__ bv,
        const float* __restrict__ wo, const float* __restrict__ bo,
        const float* __restrict__ wfc, const float* __restrict__ bfc,
        int* __restrict__ e, float* __restrict__ W2, float* __restrict__ b2,
        char* __restrict__ qp, char* __restrict__ kp, unsigned short* __restrict__ vp) {
    int bid = blockIdx.x;
    int tid = threadIdx.x;
    if (bid < 1024) {
        __shared__ __align__(16) char hbuf[10240];           // 64 tok x 80B, hi|lo halves at +0/+5120
        __shared__ __align__(16) float Cb[4][16 * 17];
        char* hHi = hbuf;
        char* hLo = hbuf + 5120;
        int wave = tid >> 6, lane = tid & 63;
        int c = lane & 15, kq = lane >> 4;

        // ---- phase A: h -> LDS hi/lo bf16 (thread = token x quarter-row) ----
        {
            int tt = tid >> 2, q4 = tid & 3;
            int idx = bid * 64 + tt;
            int b = idx >> 10, s = idx & 1023;
            float nm = (mask[b * SS + (s >= 3 ? s - 3 : 0)] != 0.0f) ? 1.0f : 0.0f;
            int tok = x[idx];
            float h[8];
#pragma unroll
            for (int i = 0; i < 8; i++)
                h[i] = (emb[tok * DD + q4 * 8 + i] + pe[s * DD + q4 * 8 + i]) * nm;
            unsigned wh[4], wl[4];
#pragma unroll
            for (int wd = 0; wd < 4; wd++) {
                float a0 = h[2 * wd], a1 = h[2 * wd + 1];
                wh[wd] = pack_hi2(a0, a1);
                wl[wd] = pack_hi2(a0 - trunc_hi(a0), a1 - trunc_hi(a1));
            }
            *(uint4*)(hHi + tt * 80 + q4 * 16) = uint4{wh[0], wh[1], wh[2], wh[3]};
            *(uint4*)(hLo + tt * 80 + q4 * 16) = uint4{wl[0], wl[1], wl[2], wl[3]};
        }
        __syncthreads();

        // ---- A-frags: wave's 16-token tile ----
        bf16x8 aHh, aHl;
        {
            int off = (wave * 16 + c) * 80 + kq * 16;
            aHh = *(const bf16x8*)(hHi + off);
            aHl = *(const bf16x8*)(hLo + off);
        }
        int blk_b = bid >> 4;
        int s_base = (bid * 64) & 1023;
        const f32x4 z4 = {0.0f, 0.0f, 0.0f, 0.0f};

#pragma unroll
        for (int M = 0; M < 3; M++) {
            const float* W    = M == 0 ? wq : (M == 1 ? wk : wv);
            const float* bias = M == 0 ? bq : (M == 1 ? bk : bv);
            bf16x8 Bh[2], Bl[2];
            float bv_[2];
#pragma unroll
            for (int nt = 0; nt < 2; nt++) {
                const float* wrow = W + (nt * 16 + c) * DD + kq * 8;
                float4 wa = ((const float4*)wrow)[0];
                float4 wb = ((const float4*)wrow)[1];
                float f[8] = {wa.x, wa.y, wa.z, wa.w, wb.x, wb.y, wb.z, wb.w};
                unsigned uh[4], ul[4];
#pragma unroll
                for (int wd = 0; wd < 4; wd++) {
                    float a0 = f[2 * wd], a1 = f[2 * wd + 1];
                    uh[wd] = pack_hi2(a0, a1);
                    ul[wd] = pack_hi2(a0 - trunc_hi(a0), a1 - trunc_hi(a1));
                }
                Bh[nt] = as_bf16x8(uint4{uh[0], uh[1], uh[2], uh[3]});
                Bl[nt] = as_bf16x8(uint4{ul[0], ul[1], ul[2], ul[3]});
                bv_[nt] = bias[nt * 16 + c];
            }
#pragma unroll
            for (int nt = 0; nt < 2; nt++) {
                f32x4 acc = __builtin_amdgcn_mfma_f32_16x16x32_bf16(aHh, Bh[nt], z4, 0, 0, 0);
                acc = __builtin_amdgcn_mfma_f32_16x16x32_bf16(aHl, Bh[nt], acc, 0, 0, 0);
                acc = __builtin_amdgcn_mfma_f32_16x16x32_bf16(aHh, Bl[nt], acc, 0, 0, 0);
#pragma unroll
                for (int r = 0; r < 4; r++) {
                    float val = acc[r] + bv_[nt];
                    if (M == 0) val *= QSC;
                    Cb[wave][(kq * 4 + r) * 17 + c] = val;
                }
                if (M < 2) {
                    // lane = token(4 groups of 16) x quarter: tl = lane>>2, qtr = lane&3
                    int tl = lane >> 2, qtr = lane & 3;
                    float f0 = Cb[wave][tl * 17 + qtr * 4 + 0];
                    float f1 = Cb[wave][tl * 17 + qtr * 4 + 1];
                    float f2 = Cb[wave][tl * 17 + qtr * 4 + 2];
                    float f3 = Cb[wave][tl * 17 + qtr * 4 + 3];
                    unsigned h0 = pack_hi2(f0, f1), h1 = pack_hi2(f2, f3);
                    unsigned l0 = pack_hi2(f0 - trunc_hi(f0), f1 - trunc_hi(f1));
                    unsigned l1 = pack_hi2(f2 - trunc_hi(f2), f3 - trunc_hi(f3));
                    int s = s_base + wave * 16 + tl;
                    char* dst = (M == 0 ? qp : kp)
                              + ((size_t)((blk_b * 2 + nt) * 1024 + s)) * 64;
                    *(uint2*)(dst + qtr * 8)      = uint2{h0, h1};
                    *(uint2*)(dst + 32 + qtr * 8) = uint2{l0, l1};
                } else {
                    // V: [row = b*32 + nt*16 + dh][key] hi-only
                    int dh = lane & 15, kg = lane >> 4;   // 4 tokens per lane
                    unsigned h0, h1;
                    {
                        float f0 = Cb[wave][(kg * 4 + 0) * 17 + dh];
                        float f1 = Cb[wave][(kg * 4 + 1) * 17 + dh];
                        float f2 = Cb[wave][(kg * 4 + 2) * 17 + dh];
                        float f3 = Cb[wave][(kg * 4 + 3) * 17 + dh];
                        h0 = pack_hi2(f0, f1); h1 = pack_hi2(f2, f3);
                    }
                    int srow = blk_b * 32 + nt * 16 + dh;
                    int scol = s_base + wave * 16 + kg * 4;
                    *(uint2*)(vp + (size_t)srow * 1024 + scol) = uint2{h0, h1};
                }
            }
        }
    } else if (bid < 1088) {
        int b = bid - 1024;
        int lm = -1;
        for (int s = tid; s < SS; s += 256)
            if (mask[b * SS + s] != 0.0f) lm = s;
        __shared__ int red[256];
        red[tid] = lm;
        __syncthreads();
        for (int off = 128; off > 0; off >>= 1) {
            if (tid < off) red[tid] = max(red[tid], red[tid + off]);
            __syncthreads();
        }
        if (tid == 0) {
            int last = red[0];
            int ee = last;
            if (last < SS - 1) ee = min(last + 3, SS - 1);
            e[b] = ee;   // kmax = e+1
        }
    } else {
        for (int t2 = tid; t2 < VV * DD + VV; t2 += 256) {
            if (t2 < VV * DD) {
                int vv = t2 / DD, i = t2 % DD;
                float a = 0.0f;
                for (int j = 0; j < DD; j++) a += wfc[vv * DD + j] * wo[j * DD + i];
                W2[t2] = a;
            } else {
                int vv = t2 - VV * DD;
                float a = bfc[vv];
                for (int j = 0; j < DD; j++) a += wfc[vv * DD + j] * bo[j];
                b2[vv] = a;
            }
        }
    }
}

// ---------------- kernel 2: split-K MFMA attention, deferred (split-scope) softmax ----------------
// grid (32 qt, 64 b, 4 sp). Split covers keys [sp*256, +256) ∩ [0,kmax) = up to 4 chunks of 64.
__global__ __launch_bounds__(256) void k_attn(
        const char* __restrict__ qp, const char* __restrict__ kp,
        const unsigned short* __restrict__ vp, const int* __restrict__ e,
        float* __restrict__ pml, unsigned short* __restrict__ pacch) {
    __shared__ __align__(16) char Pb[36864];   // 4 waves x 4 chunks x (16 rows x 144B)
    int tid = threadIdx.x;
    int qt = blockIdx.x, b = blockIdx.y, sp = blockIdx.z;
    int kmax = e[b] + 1;
    int k0 = sp * KCH;
    if (k0 >= kmax) return;                    // block-uniform early exit
    int k1 = min(k0 + KCH, kmax);
    int nit = (k1 - k0 + 63) >> 6;             // 1..4 live chunks (uniform)

    int wave = tid >> 6, lane = tid & 63, quad = lane >> 4, c = lane & 15;
    int h = wave & 1;
    int qbase = qt * 32 + (wave >> 1) * 16;
    int bh = b * 2 + h;

    bf16x8 aQ = *(const bf16x8*)(qp + ((size_t)(bh * 1024 + qbase + c)) * 64 + quad * 16);
    const char* kb = kp + ((size_t)(bh * 1024 + 4 * c)) * 64 + (quad & 1) * 16;
    const unsigned short* vb = vp + ((size_t)(b * 32 + h * 16 + c)) * 1024 + quad * 8;
    char* Pw = Pb + wave * 9216;

    const f32x4 z4 = {0.0f, 0.0f, 0.0f, 0.0f};
    f32x4 accO = z4;

    // ---- V loads for all 4 chunks (always in-bounds; issued early) ----
    bf16x8 bv0[4], bv1[4];
#pragma unroll
    for (int it = 0; it < 4; it++) {
        const unsigned short* vkt = vb + k0 + it * 64;
        bv0[it] = *(const bf16x8*)(vkt);
        bv1[it] = *(const bf16x8*)(vkt + 32);
    }

    // ---- phase 1: all scores into registers (independent loads + MFMAs) ----
    f32x4 st[4][4];
#pragma unroll
    for (int it = 0; it < 4; it++) {
        if (it < nit) {
            const char* ktb = kb + (size_t)(k0 + it * 64) * 64;
#pragma unroll
            for (int t = 0; t < 4; t++) {
                bf16x8 bkh = *(const bf16x8*)(ktb + t * 64);
                bf16x8 bkl = *(const bf16x8*)(ktb + t * 64 + 32);
                f32x4 sv = __builtin_amdgcn_mfma_f32_16x16x32_bf16(aQ, bkl, z4, 0, 0, 0);
                sv = __builtin_amdgcn_mfma_f32_16x16x32_bf16(aQ, bkh, sv, 0, 0, 0);
                if (it == nit - 1) {           // tail mask possible only in last live chunk
                    int key = k0 + it * 64 + 4 * c + t;
                    if (key >= kmax) { sv[0] = -3e38f; sv[1] = -3e38f; sv[2] = -3e38f; sv[3] = -3e38f; }
                }
                st[it][t] = sv;
            }
        } else {
#pragma unroll
            for (int t = 0; t < 4; t++) st[it][t] = f32x4{-3e38f, -3e38f, -3e38f, -3e38f};
        }
    }

    // ---- one max for the whole split ----
    float tmax = -3e38f;
#pragma unroll
    for (int it = 0; it < 4; it++)
#pragma unroll
        for (int t = 0; t < 4; t++) {
            f32x4 sv = st[it][t];
            tmax = fmaxf(tmax, fmaxf(fmaxf(sv[0], sv[1]), fmaxf(sv[2], sv[3])));
        }
#pragma unroll
    for (int d = 1; d < 64; d <<= 1) tmax = fmaxf(tmax, __shfl_xor(tmax, d));

    // ---- exp2 + pack + l (per live chunk) ----
    float l_[4] = {0.0f, 0.0f, 0.0f, 0.0f};
#pragma unroll
    for (int it = 0; it < 4; it++) {
        if (it < nit) {
            float p[4][4];
#pragma unroll
            for (int t = 0; t < 4; t++)
#pragma unroll
                for (int r = 0; r < 4; r++) p[t][r] = exp2f(st[it][t][r] - tmax);
#pragma unroll
            for (int r = 0; r < 4; r++) {
                l_[r] += (p[0][r] + p[1][r]) + (p[2][r] + p[3][r]);
                unsigned lo = pack_hi2(p[0][r], p[1][r]);
                unsigned hi = pack_hi2(p[2][r], p[3][r]);
                *(uint2*)(Pw + it * 2304 + (quad * 4 + r) * 144 + c * 8) = uint2{lo, hi};
            }
        }
    }

    // ---- PV (per live chunk; per-chunk LDS buffers -> independent chains) ----
#pragma unroll
    for (int it = 0; it < 4; it++) {
        if (it < nit) {
            const char* Pra = Pw + it * 2304 + c * 144 + quad * 16;
            bf16x8 aP0 = *(const bf16x8*)(Pra);
            bf16x8 aP1 = *(const bf16x8*)(Pra + 64);
            accO = __builtin_amdgcn_mfma_f32_16x16x32_bf16(aP0, bv0[it], accO, 0, 0, 0);
            accO = __builtin_amdgcn_mfma_f32_16x16x32_bf16(aP1, bv1[it], accO, 0, 0, 0);
        }
    }

    // ---- reduce l over key-columns; write partials ----
#pragma unroll
    for (int d = 1; d < 16; d <<= 1) {
#pragma unroll
        for (int r = 0; r < 4; r++) l_[r] += __shfl_xor(l_[r], d, 16);
    }
#pragma unroll
    for (int r = 0; r < 4; r++) {
        int q = qbase + quad * 4 + r;
        size_t pi = ((size_t)bh * SS + q) * NSPLIT + sp;
        pacch[pi * 16 + c] = bf_rtne(accO[r]);
        if (c == 0) { pml[pi * 2] = tmax; pml[pi * 2 + 1] = l_[r]; }
    }
}

// ---------------- kernel 3: combine partials + out = O @ W2^T + b2 ----------------
// 512 blocks x 256: thread = (token, head) for combine; (token, vocab-half) for FC.
__global__ __launch_bounds__(256) void k_fc(
        const float* __restrict__ pml, const unsigned short* __restrict__ pacch,
        const int* __restrict__ e,
        const float* __restrict__ W2, const float* __restrict__ b2,
        float* __restrict__ out) {
    __shared__ float Ob[128 * 36];
    __shared__ float sW[VV * 36];
    __shared__ float sb[VV];
    int tid = threadIdx.x;
    for (int i = tid; i < VV * DD; i += 256) sW[(i >> 5) * 36 + (i & 31)] = W2[i];
    if (tid < VV) sb[tid] = b2[tid];

    int tl = tid >> 1, hh = tid & 1;
    int idx = blockIdx.x * 128 + tl;
    int b = idx >> 10, s = idx & 1023;
    int nsp = min(NSPLIT, (e[b] + 256) >> 8);   // ceil((e+1)/256)

    size_t base = ((size_t)(b * 2 + hh) * SS + s) * NSPLIT;
    float mm[NSPLIT], ll[NSPLIT];
#pragma unroll
    for (int sp = 0; sp < NSPLIT; sp++) {
        if (sp < nsp) { mm[sp] = pml[(base + sp) * 2]; ll[sp] = pml[(base + sp) * 2 + 1]; }
        else          { mm[sp] = -3e38f;               ll[sp] = 0.0f; }
    }
    float M = fmaxf(fmaxf(mm[0], mm[1]), fmaxf(mm[2], mm[3]));
    float w[NSPLIT];
    float l = 0.0f;
#pragma unroll
    for (int sp = 0; sp < NSPLIT; sp++) {
        w[sp] = (sp < nsp) ? exp2f(mm[sp] - M) : 0.0f;
        l += ll[sp] * w[sp];
    }
    float inv = 1.0f / l;
    float o16[DHH];
#pragma unroll
    for (int i = 0; i < DHH; i++) o16[i] = 0.0f;
#pragma unroll
    for (int sp = 0; sp < NSPLIT; sp++) {
        if (sp < nsp) {
            const unsigned short* pr = pacch + (base + sp) * 16;
#pragma unroll
            for (int i = 0; i < DHH; i++) o16[i] += bf2f(pr[i]) * w[sp];
        }
    }
#pragma unroll
    for (int i = 0; i < DHH; i++) Ob[tl * 36 + hh * DHH + i] = o16[i] * inv;
    __syncthreads();

    // FC: thread = (token, vocab half)
    const float* orow = Ob + tl * 36;
    float ov[DD];
#pragma unroll
    for (int i = 0; i < DD; i += 4) {
        float4 t4 = *(const float4*)(orow + i);
        ov[i] = t4.x; ov[i + 1] = t4.y; ov[i + 2] = t4.z; ov[i + 3] = t4.w;
    }
    size_t obase = (size_t)idx * VV + hh * 14;
#pragma unroll
    for (int jj = 0; jj < 14; jj++) {
        int vv = hh * 14 + jj;
        float a = sb[vv];
#pragma unroll
        for (int d = 0; d < DD; d += 4) {
            float4 w4 = *(const float4*)(sW + vv * 36 + d);
            a += ov[d] * w4.x + ov[d + 1] * w4.y + ov[d + 2] * w4.z + ov[d + 3] * w4.w;
        }
        out[obase + jj] = a;
    }
}

extern "C" void kernel_launch(void* const* d_in, const int* in_sizes, int n_in,
                              void* d_out, int out_size, void* d_ws, size_t ws_size,
                              hipStream_t stream) {
    const int*   x    = (const int*)d_in[0];
    const float* mask = (const float*)d_in[1];
    const float* emb  = (const float*)d_in[2];
    const float* pe   = (const float*)d_in[3];
    const float* wq   = (const float*)d_in[4];
    const float* bq   = (const float*)d_in[5];
    const float* wk   = (const float*)d_in[6];
    const float* bk   = (const float*)d_in[7];
    const float* wv   = (const float*)d_in[8];
    const float* bv   = (const float*)d_in[9];
    const float* wo   = (const float*)d_in[10];
    const float* bo   = (const float*)d_in[11];
    const float* wfc  = (const float*)d_in[12];
    const float* bfc  = (const float*)d_in[13];
    float* out = (float*)d_out;

    char* ws = (char*)d_ws;
    int*   e  = (int*)ws;                                     // 256 B
    float* W2 = (float*)(ws + 256);
    float* b2 = (float*)(ws + 3840);
    char*  qp = ws + 4096;                                    // 8 MiB
    char*  kp = qp + (size_t)BB * HH * SS * 64;               // 8 MiB
    unsigned short* vp = (unsigned short*)(kp + (size_t)BB * HH * SS * 64);  // 4 MiB
    float* pml = (float*)(ws + 4096 + 20971520);              // 4 MiB: [pi]{m,l}
    unsigned short* pacch = (unsigned short*)((char*)pml + (size_t)BB * HH * SS * NSPLIT * 8);  // 16.8 MiB

    hipLaunchKernelGGL(k_pre, dim3(1089), dim3(256), 0, stream,
                       x, mask, emb, pe, wq, bq, wk, bk, wv, bv, wo, bo, wfc, bfc,
                       e, W2, b2, qp, kp, vp);
    hipLaunchKernelGGL(k_attn, dim3(SS / 32, BB, NSPLIT), dim3(256), 0, stream,
                       qp, kp, vp, e, pml, pacch);
    hipLaunchKernelGGL(k_fc, dim3(BB * SS / 128), dim3(256), 0, stream,
                       pml, pacch, e, W2, b2, out);
}